// Round 7
// baseline (67.159 us; speedup 1.0000x reference)
//
#include <hip/hip_runtime.h>
#include <hip/hip_bf16.h>

// Problem constants
#define Dm   1024
#define Hh   16
#define HDq  64
#define DKV  512
#define HID  128
#define Bb   2
#define Ll   2048
#define Ff   32

typedef _Float16 half8 __attribute__((ext_vector_type(8)));
typedef float f32x4 __attribute__((ext_vector_type(4)));

__device__ __forceinline__ float gelu_exact(float x) {
    return 0.5f * x * (1.0f + erff(x * 0.70710678118654752f));
}

// ---------------------------------------------------------------------------
// kpart: grid 48.
//   bx 0..31 : w1 hidden partials (b, which, jsplit) -> hid_part
//   bx 32..47: Qc partials (b, jsplit) -> qc_part   (coalesced full-row Wq)
// ---------------------------------------------------------------------------
__global__ __launch_bounds__(256) void kpart(
        const float* __restrict__ h, const float* __restrict__ Wq,
        const float* __restrict__ tw1, const float* __restrict__ dw1,
        float* __restrict__ hid_part, float* __restrict__ qc_part)
{
    const int bx = blockIdx.x, t = threadIdx.x;
    __shared__ float hl[128];
    __shared__ float red[256];
    if (bx < 32) {
        const int id = bx;
        const int b = (id >> 4) & 1, which = (id >> 3) & 1, jsplit = id & 7;
        const float* w1 = which ? dw1 : tw1;
        const float* hrow = h + ((size_t)b * Ll + (Ll - 1)) * Dm + jsplit * 128;
        if (t < 128) hl[t] = hrow[t];
        __syncthreads();
        const int col = t & 127, rg = t >> 7;
        const float* w1p = w1 + (size_t)(jsplit * 128 + rg + 1) * HID + col;
        float acc = 0.f;
#pragma unroll 8
        for (int p = 0; p < 64; ++p)
            acc += hl[p * 2 + rg] * w1p[(size_t)p * 2 * HID];
        red[t] = acc;
        __syncthreads();
        if (t < 128)
            hid_part[(((size_t)(b * 2 + which)) * 8 + jsplit) * HID + t] = red[t] + red[t + 128];
    } else {
        const int id = bx - 32;
        const int b = id >> 3, jsplit = id & 7;
        const float* hrow = h + ((size_t)b * Ll + (Ll - 1)) * Dm + jsplit * 128;
        if (t < 128) hl[t] = hrow[t];
        __syncthreads();
        // coalesced: thread t accumulates Wq cols t*4..t*4+3 over 128 rows
        float4 acc = {0.f, 0.f, 0.f, 0.f};
        const float* Wq0 = Wq + (size_t)(jsplit * 128) * Dm + t * 4;
#pragma unroll 8
        for (int j = 0; j < 128; ++j) {
            const float x = hl[j];
            float4 wq = *(const float4*)(Wq0 + (size_t)j * Dm);
            acc.x += x * wq.x; acc.y += x * wq.y;
            acc.z += x * wq.z; acc.w += x * wq.w;
        }
        const int col = t * 4;
        if ((col & 63) < 32) {            // keep only d<32 half of each head
            const int c = (col >> 6) * 32 + (col & 31);
            *(float4*)(qc_part + ((size_t)b * 8 + jsplit) * DKV + c) = acc;
        }
    }
}

// ---------------------------------------------------------------------------
// kkw2: grid (32 jt, Bb). Each block redundantly computes w_comb[b][0..512)
// (tau MLP finalize + delta matvec + Qc combine), then its 32-row Wk slice:
// kwh[b][head][j] = sum_d Wk[j][head*32+d] * w_comb[b][head*32+d]  -> fp16 chunk
// ---------------------------------------------------------------------------
__global__ __launch_bounds__(256) void kkw2(
        const float* __restrict__ mu, const float* __restrict__ sigma,
        const float* __restrict__ tw1, const float* __restrict__ tb1,
        const float* __restrict__ tw2, const float* __restrict__ tb2,
        const float* __restrict__ dw1, const float* __restrict__ db1,
        const float* __restrict__ dw2, const float* __restrict__ db2,
        const float* __restrict__ Wk,
        const float* __restrict__ hid_part, const float* __restrict__ qc_part,
        _Float16* __restrict__ kwh16)
{
    const int jt = blockIdx.x, b = blockIdx.y;
    const int t = threadIdx.x;
    __shared__ float gh[HID];
    __shared__ float red[256];
    __shared__ float wc[DKV];
    __shared__ float kl[16][36];
    __shared__ float s_tau, s_sm, s_mm;

    if (t == 0) {
        float s = 0.f;
        for (int f = 0; f < Ff; ++f) s += sigma[((size_t)b * Ll + (Ll - 1)) * Ff + f];
        s_sm = fmaxf(s / (float)Ff, 1e-6f);
    }
    if (t == 64) {
        float s = 0.f;
        for (int f = 0; f < Ff; ++f) s += mu[((size_t)b * Ll + (Ll - 1)) * Ff + f];
        s_mm = s / (float)Ff;
    }
    __syncthreads();

    if (t < 128) {
        float a = tb1[t] + s_sm * tw1[t];
#pragma unroll
        for (int s = 0; s < 8; ++s)
            a += hid_part[(((size_t)(b * 2 + 0)) * 8 + s) * HID + t];
        red[t] = gelu_exact(a) * tw2[t];
    } else {
        const int hh = t - 128;
        float a = db1[hh] + s_mm * dw1[hh];
#pragma unroll
        for (int s = 0; s < 8; ++s)
            a += hid_part[(((size_t)(b * 2 + 1)) * 8 + s) * HID + hh];
        gh[hh] = gelu_exact(a);
        red[t] = 0.f;
    }
    __syncthreads();
    for (int s = 128; s > 0; s >>= 1) {
        if (t < s) red[t] += red[t + s];
        __syncthreads();
    }
    if (t == 0) {
        float s = red[0] + tb2[0];
        s_tau = expf(fminf(fmaxf(s, -3.f), 3.f));
    }
    __syncthreads();

    // full w_comb into LDS (c0 = t, c1 = t+256)
    const int c0 = t, c1 = t + 256;
    float d0 = db2[c0], d1 = db2[c1];
#pragma unroll 8
    for (int i = 0; i < HID; ++i) {
        const float x = gh[i];
        d0 += x * dw2[(size_t)i * DKV + c0];
        d1 += x * dw2[(size_t)i * DKV + c1];
    }
    d0 = fminf(fmaxf(d0, -5.f), 5.f);
    d1 = fminf(fmaxf(d1, -5.f), 5.f);
    float q0 = 0.f, q1 = 0.f;
#pragma unroll
    for (int s = 0; s < 8; ++s) {
        const float* qp = qc_part + ((size_t)b * 8 + s) * DKV;
        q0 += qp[c0];
        q1 += qp[c1];
    }
    const float inv_sqrt = 0.17677669529663687f;
    wc[c0] = s_tau * q0 * inv_sqrt + d0;
    wc[c1] = s_tau * q1 * inv_sqrt + d1;
    __syncthreads();

    // Wk slice: 32 j rows -> one fp16 chunk
    const float w0 = wc[t * 2], w1 = wc[t * 2 + 1];
    const int hd = t >> 4;
#pragma unroll 4
    for (int jj = 0; jj < 32; ++jj) {
        const int j = jt * 32 + jj;
        float2 kv = *(const float2*)(Wk + (size_t)j * DKV + t * 2);
        float p = kv.x * w0 + kv.y * w1;
        p += __shfl_xor(p, 1); p += __shfl_xor(p, 2);
        p += __shfl_xor(p, 4); p += __shfl_xor(p, 8);
        if ((t & 15) == 0) kl[hd][jj] = p;
    }
    __syncthreads();
    if (t < 64) {
        const int head = t & 15, jl = (t >> 4) * 8;
        half8 v;
#pragma unroll
        for (int e = 0; e < 8; ++e) v[e] = (_Float16)kl[head][jl + e];
        *(half8*)(kwh16 + ((size_t)(b * 32 + jt)) * 512 + t * 8) = v;
    }
}

// ---------------------------------------------------------------------------
// kmid: fused logits + exp + den + P-weighted h accumulation.
// grid (64 rt, Bb): 32 rows per block.
//  phase 1: logits[row][head] via MFMA (4-wave k-split), exp(val-50) -> p_lds
//  phase 2: hbar_part[b][rt][h][j] = sum_{l<32} p[l][h] * h[row0+l][j]  (f32)
// ---------------------------------------------------------------------------
__global__ __launch_bounds__(256) void kmid(
        const float* __restrict__ h, const _Float16* __restrict__ kwh16,
        float* __restrict__ den_part, float* __restrict__ hbar_part)
{
    __shared__ __align__(16) _Float16 Kw[16384];      // 32 KB
    __shared__ float lred[4][32][17];                 // padded: conflict-free
    __shared__ float p_lds[32][16];
    const int rt = blockIdx.x, b = blockIdx.y;
    const int t = threadIdx.x;
    const int w = t >> 6, l = t & 63;
    const int rows0 = (b * 64 + rt) * 32;             // global h row base

    // stage kwh16[b] (32 KB) to LDS
#pragma unroll
    for (int i = 0; i < 8; ++i) {
        const int idx = i * 256 + t;
        *(half8*)(Kw + idx * 8) = *(const half8*)(kwh16 + (size_t)b * 16384 + idx * 8);
    }
    __syncthreads();

    // phase 1: 2 m-tiles x 8 k-steps per wave
    f32x4 lacc[2] = {};
    const float* ap = h + (size_t)(rows0 + (l & 15)) * Dm + (l >> 4) * 8;
#pragma unroll
    for (int mt = 0; mt < 2; ++mt) {
        const float* apm = ap + (size_t)mt * 16 * Dm;
#pragma unroll
        for (int ks = 0; ks < 8; ++ks) {
            const int kt = w * 8 + ks;
            float4 x0 = *(const float4*)(apm + kt * 32);
            float4 x1 = *(const float4*)(apm + kt * 32 + 4);
            half8 af;
            af[0] = (_Float16)x0.x; af[1] = (_Float16)x0.y; af[2] = (_Float16)x0.z; af[3] = (_Float16)x0.w;
            af[4] = (_Float16)x1.x; af[5] = (_Float16)x1.y; af[6] = (_Float16)x1.z; af[7] = (_Float16)x1.w;
            half8 kf = *(const half8*)(Kw + kt * 512 + l * 8);
            lacc[mt] = __builtin_amdgcn_mfma_f32_16x16x32_f16(af, kf, lacc[mt], 0, 0, 0);
        }
    }
#pragma unroll
    for (int mt = 0; mt < 2; ++mt)
#pragma unroll
        for (int r = 0; r < 4; ++r)
            lred[w][mt * 16 + (l >> 4) * 4 + r][l & 15] = lacc[mt][r];
    __syncthreads();

#pragma unroll
    for (int i = 0; i < 2; ++i) {
        const int row = i * 16 + (t >> 4), head = t & 15;
        float val = lred[0][row][head] + lred[1][row][head]
                  + lred[2][row][head] + lred[3][row][head];
        val = fminf(fmaxf(val, -50.f), 50.f);
        p_lds[row][head] = __expf(val - 50.f);
    }
    __syncthreads();

    if (t < 16) {
        float s = 0.f;
#pragma unroll
        for (int r = 0; r < 32; ++r) s += p_lds[r][t];
        den_part[((size_t)b * Hh + t) * 64 + rt] = s;
    }

    // phase 2: thread covers 16 j (4 float4) x 4 heads
    const int j0 = (t & 63) * 16;
    const int h0 = (t >> 6) * 4;                      // wave-uniform
    f32x4 acc[4][4] = {};                             // [jj][hh]
    for (int l2 = 0; l2 < 32; ++l2) {
        const float* hr = h + (size_t)(rows0 + l2) * Dm + j0;
        f32x4 hv[4];
#pragma unroll
        for (int jj = 0; jj < 4; ++jj) hv[jj] = *(const f32x4*)(hr + jj * 4);
        f32x4 pp = *(const f32x4*)(&p_lds[l2][h0]);
#pragma unroll
        for (int hh = 0; hh < 4; ++hh)
#pragma unroll
            for (int jj = 0; jj < 4; ++jj)
                acc[jj][hh] += hv[jj] * pp[hh];
    }
#pragma unroll
    for (int hh = 0; hh < 4; ++hh) {
        float* dst = hbar_part + (((size_t)(b * 64 + rt)) * Hh + h0 + hh) * Dm + j0;
#pragma unroll
        for (int jj = 0; jj < 4; ++jj)
            *(f32x4*)(dst + jj * 4) = acc[jj][hh];
    }
}

// ---------------------------------------------------------------------------
// kopre: grid (16 h, Bb). hbar = sum_rt parts; den = sum_rt den_part;
// opre[b][h*32+d] = (sum_j hbar[j]*Wv[j][h*32+d]) / den
// ---------------------------------------------------------------------------
__global__ __launch_bounds__(256) void kopre(
        const float* __restrict__ hbar_part, const float* __restrict__ den_part,
        const float* __restrict__ Wv, float* __restrict__ opre)
{
    const int hd = blockIdx.x, b = blockIdx.y;
    const int t = threadIdx.x;
    __shared__ float hb[Dm];
    __shared__ float red[256];
    __shared__ float dred[64];
    __shared__ float s_den;

    if (t >= 192) dred[t - 192] = den_part[((size_t)b * Hh + hd) * 64 + (t - 192)];
    f32x4 a = {};
#pragma unroll 8
    for (int rt = 0; rt < 64; ++rt)
        a += *(const f32x4*)(hbar_part + (((size_t)(b * 64 + rt)) * Hh + hd) * Dm + t * 4);
    *(f32x4*)(hb + t * 4) = a;
    __syncthreads();
    if (t < 32) dred[t] += dred[t + 32];
    __syncthreads();
    if (t == 0) {
        float s = 0.f;
        for (int i = 0; i < 32; ++i) s += dred[i];
        s_den = s;
    }
    __syncthreads();

    const int c = hd * 32 + (t & 31);
    float accv = 0.f;
    const int jbase = (t >> 5) * 128;
#pragma unroll 8
    for (int j = jbase; j < jbase + 128; ++j)
        accv += hb[j] * Wv[(size_t)j * DKV + c];
    red[t] = accv;
    __syncthreads();
    if (t < 32) {
        float s = 0.f;
#pragma unroll
        for (int g = 0; g < 8; ++g) s += red[g * 32 + t];
        opre[((size_t)b * Hh + hd) * 32 + t] = s / s_den;
    }
}

// ---------------------------------------------------------------------------
// kout: out[b][n] = bo[n] + sum_c opre[b][c] * Wo[c][n]. grid (16 nt, Bb)
// ---------------------------------------------------------------------------
__global__ __launch_bounds__(256) void kout(
        const float* __restrict__ opre, const float* __restrict__ Wo,
        const float* __restrict__ bo, float* __restrict__ out)
{
    const int nt = blockIdx.x, b = blockIdx.y;
    const int t = threadIdx.x;
    __shared__ float op[DKV];
    __shared__ float red[256];
    if (t < 128)
        *(float4*)(op + t * 4) = *(const float4*)(opre + (size_t)b * DKV + t * 4);
    __syncthreads();
    const int nl = t & 63, cg = t >> 6;
    const int n = nt * 64 + nl;
    float acc = 0.f;
#pragma unroll 8
    for (int c = cg * 128; c < cg * 128 + 128; ++c)
        acc += op[c] * Wo[(size_t)c * Dm + n];
    red[t] = acc;
    __syncthreads();
    if (t < 64)
        out[(size_t)b * Dm + n] = bo[n] + red[t] + red[t + 64] + red[t + 128] + red[t + 192];
}

// ---------------------------------------------------------------------------
extern "C" void kernel_launch(void* const* d_in, const int* in_sizes, int n_in,
                              void* d_out, int out_size, void* d_ws, size_t ws_size,
                              hipStream_t stream) {
    const float* h      = (const float*)d_in[0];
    const float* mu     = (const float*)d_in[1];
    const float* sigma  = (const float*)d_in[2];
    const float* Wq     = (const float*)d_in[3];
    const float* Wk     = (const float*)d_in[4];
    const float* Wv     = (const float*)d_in[5];
    const float* Wo     = (const float*)d_in[6];
    const float* bo     = (const float*)d_in[7];
    const float* tau_w1 = (const float*)d_in[8];
    const float* tau_b1 = (const float*)d_in[9];
    const float* tau_w2 = (const float*)d_in[10];
    const float* tau_b2 = (const float*)d_in[11];
    const float* del_w1 = (const float*)d_in[12];
    const float* del_b1 = (const float*)d_in[13];
    const float* del_w2 = (const float*)d_in[14];
    const float* del_b2 = (const float*)d_in[15];
    float* out = (float*)d_out;

    // workspace (~8.2 MB)
    _Float16* kwh16  = (_Float16*)d_ws;                     // 2*32*512 = 32768 halfs
    float* den_part  = (float*)(kwh16 + 32768);             // 2*16*64 = 2048
    float* hid_part  = den_part + 2048;                     // 4096
    float* qc_part   = hid_part + 4096;                     // 8192
    float* opre      = qc_part + 8192;                      // 1024
    float* hbar_part = opre + 1024;                         // 2*64*16*1024 = 2M f32

    kpart<<<48, 256, 0, stream>>>(h, Wq, tau_w1, del_w1, hid_part, qc_part);
    kkw2<<<dim3(32, Bb), 256, 0, stream>>>(mu, sigma, tau_w1, tau_b1, tau_w2, tau_b2,
                                           del_w1, del_b1, del_w2, del_b2, Wk,
                                           hid_part, qc_part, kwh16);
    kmid<<<dim3(64, Bb), 256, 0, stream>>>(h, kwh16, den_part, hbar_part);
    kopre<<<dim3(16, Bb), 256, 0, stream>>>(hbar_part, den_part, Wv, opre);
    kout<<<dim3(16, Bb), 256, 0, stream>>>(opre, Wo, bo, out);
}

// Round 8
// 52.042 us; speedup vs baseline: 1.2905x; 1.2905x over previous
//
#include <hip/hip_runtime.h>
#include <hip/hip_bf16.h>

// Problem constants
#define Dm   1024
#define Hh   16
#define HDq  64
#define DKV  512
#define HID  128
#define Bb   2
#define Ll   2048
#define Ff   32

typedef _Float16 half8 __attribute__((ext_vector_type(8)));
typedef float f32x4 __attribute__((ext_vector_type(4)));

__device__ __forceinline__ float gelu_exact(float x) {
    return 0.5f * x * (1.0f + erff(x * 0.70710678118654752f));
}

// ---------------------------------------------------------------------------
// kpart: grid 192.
//   bx 0..127   : w1 hidden partials (b, which, js=0..31; 32 rows each)
//   bx 128..191 : Qc partials (b, js=0..31; 32 rows each), coalesced Wq rows
// ---------------------------------------------------------------------------
__global__ __launch_bounds__(256) void kpart(
        const float* __restrict__ h, const float* __restrict__ Wq,
        const float* __restrict__ tw1, const float* __restrict__ dw1,
        float* __restrict__ hid_part, float* __restrict__ qc_part)
{
    const int bx = blockIdx.x, t = threadIdx.x;
    __shared__ float hl[32];
    __shared__ float red[256];
    if (bx < 128) {
        const int b = bx >> 6, which = (bx >> 5) & 1, js = bx & 31;
        const float* w1 = which ? dw1 : tw1;
        const float* hrow = h + ((size_t)b * Ll + (Ll - 1)) * Dm + js * 32;
        if (t < 32) hl[t] = hrow[t];
        __syncthreads();
        const int col = t & 127, rg = t >> 7;
        float acc = 0.f;
#pragma unroll
        for (int p = 0; p < 16; ++p) {
            const int row = p * 2 + rg;
            acc += hl[row] * w1[(size_t)(js * 32 + row + 1) * HID + col];
        }
        red[t] = acc;
        __syncthreads();
        if (t < 128)
            hid_part[((size_t)(b * 2 + which) * 32 + js) * HID + t] = red[t] + red[t + 128];
    } else {
        const int id = bx - 128;
        const int b = id >> 5, js = id & 31;
        const float* hrow = h + ((size_t)b * Ll + (Ll - 1)) * Dm + js * 32;
        if (t < 32) hl[t] = hrow[t];
        __syncthreads();
        float4 acc = {0.f, 0.f, 0.f, 0.f};
        const float* Wq0 = Wq + (size_t)(js * 32) * Dm + t * 4;
#pragma unroll
        for (int j = 0; j < 32; ++j) {
            const float x = hl[j];
            float4 wq = *(const float4*)(Wq0 + (size_t)j * Dm);
            acc.x += x * wq.x; acc.y += x * wq.y;
            acc.z += x * wq.z; acc.w += x * wq.w;
        }
        const int col = t * 4;
        if ((col & 63) < 32) {            // keep only d<32 half of each head
            const int c = (col >> 6) * 32 + (col & 31);
            *(float4*)(qc_part + ((size_t)b * 32 + js) * DKV + c) = acc;
        }
    }
}

// ---------------------------------------------------------------------------
// kkw2: grid (32 jt, Bb). Each block redundantly finalizes w_comb[b][0..512)
// (tau MLP + delta matvec + Qc combine), then its 32-row Wk slice -> fp16 chunk:
// kwh[b][head][j] = sum_d Wk[j][head*32+d] * w_comb[b][head*32+d]
// ---------------------------------------------------------------------------
__global__ __launch_bounds__(256) void kkw2(
        const float* __restrict__ mu, const float* __restrict__ sigma,
        const float* __restrict__ tw1, const float* __restrict__ tb1,
        const float* __restrict__ tw2, const float* __restrict__ tb2,
        const float* __restrict__ dw1, const float* __restrict__ db1,
        const float* __restrict__ dw2, const float* __restrict__ db2,
        const float* __restrict__ Wk,
        const float* __restrict__ hid_part, const float* __restrict__ qc_part,
        _Float16* __restrict__ kwh16)
{
    const int jt = blockIdx.x, b = blockIdx.y;
    const int t = threadIdx.x;
    __shared__ float gh[HID];
    __shared__ float red[256];
    __shared__ float wc[DKV];
    __shared__ float kl[16][36];
    __shared__ float s_tau, s_sm, s_mm;

    if (t == 0) {
        float s = 0.f;
        for (int f = 0; f < Ff; ++f) s += sigma[((size_t)b * Ll + (Ll - 1)) * Ff + f];
        s_sm = fmaxf(s / (float)Ff, 1e-6f);
    }
    if (t == 64) {
        float s = 0.f;
        for (int f = 0; f < Ff; ++f) s += mu[((size_t)b * Ll + (Ll - 1)) * Ff + f];
        s_mm = s / (float)Ff;
    }
    __syncthreads();

    if (t < 128) {
        float a = tb1[t] + s_sm * tw1[t];
#pragma unroll
        for (int s = 0; s < 32; ++s)
            a += hid_part[((size_t)(b * 2 + 0) * 32 + s) * HID + t];
        red[t] = gelu_exact(a) * tw2[t];
    } else {
        const int hh = t - 128;
        float a = db1[hh] + s_mm * dw1[hh];
#pragma unroll
        for (int s = 0; s < 32; ++s)
            a += hid_part[((size_t)(b * 2 + 1) * 32 + s) * HID + hh];
        gh[hh] = gelu_exact(a);
        red[t] = 0.f;
    }
    __syncthreads();
    for (int s = 128; s > 0; s >>= 1) {
        if (t < s) red[t] += red[t + s];
        __syncthreads();
    }
    if (t == 0) {
        float s = red[0] + tb2[0];
        s_tau = expf(fminf(fmaxf(s, -3.f), 3.f));
    }
    __syncthreads();

    // full w_comb into LDS (c0 = t, c1 = t+256)
    const int c0 = t, c1 = t + 256;
    float d0 = db2[c0], d1 = db2[c1];
#pragma unroll 16
    for (int i = 0; i < HID; ++i) {
        const float x = gh[i];
        d0 += x * dw2[(size_t)i * DKV + c0];
        d1 += x * dw2[(size_t)i * DKV + c1];
    }
    d0 = fminf(fmaxf(d0, -5.f), 5.f);
    d1 = fminf(fmaxf(d1, -5.f), 5.f);
    float q0 = 0.f, q1 = 0.f;
#pragma unroll
    for (int s = 0; s < 32; ++s) {
        const float* qp = qc_part + ((size_t)b * 32 + s) * DKV;
        q0 += qp[c0];
        q1 += qp[c1];
    }
    const float inv_sqrt = 0.17677669529663687f;
    wc[c0] = s_tau * q0 * inv_sqrt + d0;
    wc[c1] = s_tau * q1 * inv_sqrt + d1;
    __syncthreads();

    // Wk slice: 32 j rows -> one fp16 chunk
    const float w0 = wc[t * 2], w1 = wc[t * 2 + 1];
    const int hd = t >> 4;
#pragma unroll 4
    for (int jj = 0; jj < 32; ++jj) {
        const int j = jt * 32 + jj;
        float2 kv = *(const float2*)(Wk + (size_t)j * DKV + t * 2);
        float p = kv.x * w0 + kv.y * w1;
        p += __shfl_xor(p, 1); p += __shfl_xor(p, 2);
        p += __shfl_xor(p, 4); p += __shfl_xor(p, 8);
        if ((t & 15) == 0) kl[hd][jj] = p;
    }
    __syncthreads();
    if (t < 64) {
        const int head = t & 15, jl = (t >> 4) * 8;
        half8 v;
#pragma unroll
        for (int e = 0; e < 8; ++e) v[e] = (_Float16)kl[head][jl + e];
        *(half8*)(kwh16 + ((size_t)(b * 32 + jt)) * 512 + t * 8) = v;
    }
}

// ---------------------------------------------------------------------------
// kmid: fused logits + exp + den + P-weighted h accumulation. 512 threads.
// grid (64 rt, Bb): 32 rows per block.
//  phase 1: logits[row][head] via MFMA (8-wave k-split), exp(val-50) -> p_lds
//  phase 2: hbar_part[b*64+rt][h][j] = sum_{l<32} p[l][h] * h[row0+l][j]
// ---------------------------------------------------------------------------
__global__ __launch_bounds__(512) void kmid(
        const float* __restrict__ h, const _Float16* __restrict__ kwh16,
        float* __restrict__ den_part, float* __restrict__ hbar_part)
{
    __shared__ __align__(16) _Float16 Kw[16384];      // 32 KB
    __shared__ float lred[8][32][17];                 // 17.4 KB, padded
    __shared__ float p_lds[32][16];
    const int rt = blockIdx.x, b = blockIdx.y;
    const int t = threadIdx.x;
    const int w = t >> 6, l = t & 63;
    const int rows0 = (b * 64 + rt) * 32;             // global h row base

    // stage kwh16[b] (32 KB) to LDS
#pragma unroll
    for (int i = 0; i < 4; ++i) {
        const int idx = i * 512 + t;
        *(half8*)(Kw + idx * 8) = *(const half8*)(kwh16 + (size_t)b * 16384 + idx * 8);
    }
    __syncthreads();

    // phase 1: 2 m-tiles x 4 k-steps per wave (8-wave k-split)
    f32x4 lacc[2] = {};
    const float* ap = h + (size_t)(rows0 + (l & 15)) * Dm + (l >> 4) * 8;
#pragma unroll
    for (int mt = 0; mt < 2; ++mt) {
        const float* apm = ap + (size_t)mt * 16 * Dm;
#pragma unroll
        for (int ks = 0; ks < 4; ++ks) {
            const int kt = w * 4 + ks;
            float4 x0 = *(const float4*)(apm + kt * 32);
            float4 x1 = *(const float4*)(apm + kt * 32 + 4);
            half8 af;
            af[0] = (_Float16)x0.x; af[1] = (_Float16)x0.y; af[2] = (_Float16)x0.z; af[3] = (_Float16)x0.w;
            af[4] = (_Float16)x1.x; af[5] = (_Float16)x1.y; af[6] = (_Float16)x1.z; af[7] = (_Float16)x1.w;
            half8 kf = *(const half8*)(Kw + kt * 512 + l * 8);
            lacc[mt] = __builtin_amdgcn_mfma_f32_16x16x32_f16(af, kf, lacc[mt], 0, 0, 0);
        }
    }
#pragma unroll
    for (int mt = 0; mt < 2; ++mt)
#pragma unroll
        for (int r = 0; r < 4; ++r)
            lred[w][mt * 16 + (l >> 4) * 4 + r][l & 15] = lacc[mt][r];
    __syncthreads();

    {
        const int row = t >> 4, head = t & 15;        // 512 threads = 32 x 16
        float val = 0.f;
#pragma unroll
        for (int ww = 0; ww < 8; ++ww) val += lred[ww][row][head];
        val = fminf(fmaxf(val, -50.f), 50.f);
        p_lds[row][head] = __expf(val - 50.f);
    }
    __syncthreads();

    if (t < 16) {
        float s = 0.f;
#pragma unroll
        for (int r = 0; r < 32; ++r) s += p_lds[r][t];
        den_part[((size_t)b * Hh + t) * 64 + rt] = s;
    }

    // phase 2: thread covers 8 j x 4 heads (L2-hot h re-read)
    const int j0 = (t & 127) * 8;
    const int h0 = (t >> 7) * 4;                      // wave-uniform
    f32x4 acc2[2][4] = {};                            // [j-quad][hh]
#pragma unroll 4
    for (int l2 = 0; l2 < 32; ++l2) {
        const float* hr = h + (size_t)(rows0 + l2) * Dm + j0;
        f32x4 hv0 = *(const f32x4*)hr;
        f32x4 hv1 = *(const f32x4*)(hr + 4);
        f32x4 pp = *(const f32x4*)(&p_lds[l2][h0]);
#pragma unroll
        for (int hh = 0; hh < 4; ++hh) {
            acc2[0][hh] += hv0 * pp[hh];
            acc2[1][hh] += hv1 * pp[hh];
        }
    }
#pragma unroll
    for (int hh = 0; hh < 4; ++hh) {
        float* dst = hbar_part + ((size_t)(b * 64 + rt) * Hh + h0 + hh) * Dm + j0;
        *(f32x4*)dst = acc2[0][hh];
        *(f32x4*)(dst + 4) = acc2[1][hh];
    }
}

// ---------------------------------------------------------------------------
// kopre: grid (16 h, Bb, 8 js). j-slice 128: reduce 64 rt partials, then
// Wv matvec partial -> opre_part[b][h][js][32]
// ---------------------------------------------------------------------------
__global__ __launch_bounds__(256) void kopre(
        const float* __restrict__ hbar_part, const float* __restrict__ Wv,
        float* __restrict__ opre_part)
{
    const int hd = blockIdx.x, b = blockIdx.y, js = blockIdx.z;
    const int t = threadIdx.x;
    __shared__ f32x4 pA[32][8];
    __shared__ float hb[128];
    __shared__ float red[256];

    const int slot = t >> 3, rs = t & 7;
    f32x4 a = {};
#pragma unroll
    for (int i = 0; i < 8; ++i) {
        const int rt = rs + i * 8;
        a += *(const f32x4*)(hbar_part + ((size_t)(b * 64 + rt) * Hh + hd) * Dm + js * 128 + slot * 4);
    }
    pA[slot][rs] = a;
    __syncthreads();
    if (t < 32) {
        f32x4 s = {};
#pragma unroll
        for (int r = 0; r < 8; ++r) s += pA[t][r];
        *(f32x4*)(hb + t * 4) = s;
    }
    __syncthreads();

    const int c = t & 31, jg = t >> 5;
    float acc = 0.f;
#pragma unroll
    for (int i = 0; i < 16; ++i)
        acc += hb[jg * 16 + i] * Wv[(size_t)(js * 128 + jg * 16 + i) * DKV + hd * 32 + c];
    red[t] = acc;
    __syncthreads();
    if (t < 32) {
        float s = 0.f;
#pragma unroll
        for (int g = 0; g < 8; ++g) s += red[g * 32 + t];
        opre_part[((size_t)(b * Hh + hd) * 8 + js) * 32 + t] = s;
    }
}

// ---------------------------------------------------------------------------
// kout: grid (32 nt, Bb). Finalize opre (sum js, / den) then 32-n slice of
// out = opre @ Wo + bo with 8-way c-split.
// ---------------------------------------------------------------------------
__global__ __launch_bounds__(256) void kout(
        const float* __restrict__ opre_part, const float* __restrict__ den_part,
        const float* __restrict__ Wo, const float* __restrict__ bo,
        float* __restrict__ out)
{
    const int nt = blockIdx.x, b = blockIdx.y;
    const int t = threadIdx.x;
    __shared__ float op[DKV];
    __shared__ float den_s[16];
    __shared__ float red[256];

    if (t < 16) {
        float s = 0.f;
#pragma unroll 16
        for (int rt = 0; rt < 64; ++rt)
            s += den_part[((size_t)b * Hh + t) * 64 + rt];
        den_s[t] = s;
    }
    __syncthreads();
#pragma unroll
    for (int cc = 0; cc < 2; ++cc) {
        const int c = cc * 256 + t;
        float s = 0.f;
#pragma unroll
        for (int js = 0; js < 8; ++js)
            s += opre_part[((size_t)(b * Hh + (c >> 5)) * 8 + js) * 32 + (c & 31)];
        op[c] = s / den_s[c >> 5];
    }
    __syncthreads();

    const int nl = t & 31, cg = t >> 5;
    const int n = nt * 32 + nl;
    float acc = 0.f;
#pragma unroll 16
    for (int c = cg * 64; c < cg * 64 + 64; ++c)
        acc += op[c] * Wo[(size_t)c * Dm + n];
    red[t] = acc;
    __syncthreads();
    if (t < 32) {
        float s = 0.f;
#pragma unroll
        for (int g = 0; g < 8; ++g) s += red[g * 32 + t];
        out[(size_t)b * Dm + nt * 32 + t] = bo[nt * 32 + t] + s;
    }
}

// ---------------------------------------------------------------------------
extern "C" void kernel_launch(void* const* d_in, const int* in_sizes, int n_in,
                              void* d_out, int out_size, void* d_ws, size_t ws_size,
                              hipStream_t stream) {
    const float* h      = (const float*)d_in[0];
    const float* mu     = (const float*)d_in[1];
    const float* sigma  = (const float*)d_in[2];
    const float* Wq     = (const float*)d_in[3];
    const float* Wk     = (const float*)d_in[4];
    const float* Wv     = (const float*)d_in[5];
    const float* Wo     = (const float*)d_in[6];
    const float* bo     = (const float*)d_in[7];
    const float* tau_w1 = (const float*)d_in[8];
    const float* tau_b1 = (const float*)d_in[9];
    const float* tau_w2 = (const float*)d_in[10];
    const float* tau_b2 = (const float*)d_in[11];
    const float* del_w1 = (const float*)d_in[12];
    const float* del_b1 = (const float*)d_in[13];
    const float* del_w2 = (const float*)d_in[14];
    const float* del_b2 = (const float*)d_in[15];
    float* out = (float*)d_out;

    // workspace (~8.6 MB)
    _Float16* kwh16  = (_Float16*)d_ws;                     // 2*32*512 = 32768 halfs
    float* den_part  = (float*)(kwh16 + 32768);             // 2*16*64 = 2048
    float* hid_part  = den_part + 2048;                     // 2*2*32*128 = 16384
    float* qc_part   = hid_part + 16384;                    // 2*32*512 = 32768
    float* opre_part = qc_part + 32768;                     // 2*16*8*32 = 8192
    float* hbar_part = opre_part + 8192;                    // 2*64*16*1024 = 2M f32

    kpart<<<192, 256, 0, stream>>>(h, Wq, tau_w1, del_w1, hid_part, qc_part);
    kkw2<<<dim3(32, Bb), 256, 0, stream>>>(mu, sigma, tau_w1, tau_b1, tau_w2, tau_b2,
                                           del_w1, del_b1, del_w2, del_b2, Wk,
                                           hid_part, qc_part, kwh16);
    kmid<<<dim3(64, Bb), 512, 0, stream>>>(h, kwh16, den_part, hbar_part);
    kopre<<<dim3(16, Bb, 8), 256, 0, stream>>>(hbar_part, Wv, opre_part);
    kout<<<dim3(32, Bb), 256, 0, stream>>>(opre_part, den_part, Wo, bo, out);
}